// Round 1
// baseline (291.621 us; speedup 1.0000x reference)
//
#include <hip/hip_runtime.h>
#include <hip/hip_bf16.h>

// Problem constants (from reference)
#define BQ 4
#define NN 10000
#define EE 160000
#define INF_ 64
#define HC 256      // H*OUT
#define CC 128      // OUT
#define SLOPEK 0.2f
#define CAPE 1024   // max (deg+1) per node supported in LDS (avg is 17)

// ---------------- Kernel A: xl = x@Wl+bl, xr = x@Wr+br ----------------
// grid.x = (B*N)/16 row-groups, grid.y = 2 (l / r), 256 threads = output col
__global__ __launch_bounds__(256) void k_lin(
    const float* __restrict__ x,
    const float* __restrict__ Wl, const float* __restrict__ bl,
    const float* __restrict__ Wr, const float* __restrict__ br,
    float* __restrict__ xl, float* __restrict__ xr)
{
    const int t  = threadIdx.x;          // output column 0..255
    const int r0 = blockIdx.x * 16;      // first row of this group
    const float* W; const float* bv; float* outp;
    if (blockIdx.y == 0) { W = Wl; bv = bl; outp = xl; }
    else                 { W = Wr; bv = br; outp = xr; }

    __shared__ float xs[16][64];
    for (int i = t; i < 16 * 64; i += 256)
        xs[i >> 6][i & 63] = x[(size_t)r0 * 64 + i];
    __syncthreads();

    float acc[16];
    const float b = bv[t];
#pragma unroll
    for (int r = 0; r < 16; ++r) acc[r] = b;

    for (int k = 0; k < 64; ++k) {
        const float w = W[k * HC + t];
#pragma unroll
        for (int r = 0; r < 16; ++r) acc[r] += xs[r][k] * w;
    }
#pragma unroll
    for (int r = 0; r < 16; ++r)
        outp[(size_t)(r0 + r) * HC + t] = acc[r];
}

// ---------------- Kernel B1: degree + attr sums per dst ----------------
__global__ void k_count(const int* __restrict__ ei, const float* __restrict__ ea,
                        int* __restrict__ deg, float* __restrict__ asum)
{
    int e = blockIdx.x * 256 + threadIdx.x;
    if (e < EE) {
        int d = ei[EE + e];             // dst row of edge_index
        atomicAdd(&deg[d], 1);
        atomicAdd(&asum[d], ea[e]);
    }
}

// ---------------- Kernel B2: loop_attr + exclusive scan of (deg+1) ------
__global__ __launch_bounds__(1024) void k_scan(
    const int* __restrict__ deg, const float* __restrict__ asum,
    float* __restrict__ lattr, int* __restrict__ offs)
{
    __shared__ int s[1024];
    __shared__ int run;
    const int t = threadIdx.x;
    if (t == 0) run = 0;
    __syncthreads();

    const int nchunk = (NN + 1023) / 1024;
    for (int c = 0; c < nchunk; ++c) {
        int i = c * 1024 + t;
        int v = 0;
        if (i < NN) {
            int dg = deg[i];
            v = dg + 1;
            lattr[i] = asum[i] / fmaxf((float)dg, 1.0f);
        }
        s[t] = v;
        __syncthreads();
        for (int off = 1; off < 1024; off <<= 1) {
            int add = (t >= off) ? s[t - off] : 0;
            __syncthreads();
            s[t] += add;
            __syncthreads();
        }
        int ctot = s[1023];
        if (i < NN) offs[i] = run + s[t] - v;   // exclusive
        __syncthreads();
        if (t == 0) run += ctot;
        __syncthreads();
    }
    if (t == 0) offs[NN] = run;  // == EE + NN
}

// ---------------- Kernel B3: scatter edges (+self loops) into CSR -------
__global__ void k_scatter(const int* __restrict__ ei, const float* __restrict__ ea,
                          const float* __restrict__ lattr, const int* __restrict__ offs,
                          int* __restrict__ cnt, int* __restrict__ csrc,
                          float* __restrict__ cattr)
{
    int e = blockIdx.x * 256 + threadIdx.x;
    if (e < EE) {
        int sn = ei[e];
        int d  = ei[EE + e];
        int pos = offs[d] + atomicAdd(&cnt[d], 1);
        csrc[pos]  = sn;
        cattr[pos] = ea[e];
    } else if (e < EE + NN) {
        int n = e - EE;
        int pos = offs[n] + atomicAdd(&cnt[n], 1);
        csrc[pos]  = n;
        cattr[pos] = lattr[n];
    }
}

// ---------------- Kernel C: fused logits + softmax + aggregation --------
// grid = (N, B), block = 256. Thread t owns output element t = h*128 + c.
__global__ __launch_bounds__(256) void k_gat(
    const float* __restrict__ xl, const float* __restrict__ xr,
    const int* __restrict__ offs, const int* __restrict__ csrc,
    const float* __restrict__ cattr, const float* __restrict__ We,
    const float* __restrict__ att, const float* __restrict__ bias,
    float* __restrict__ outp)
{
    const int n = blockIdx.x;
    const int b = blockIdx.y;
    const int t = threadIdx.x;

    __shared__ float sXr[HC], sWe[HC], sAtt[HC];
    __shared__ float sAlpha[2][CAPE];
    __shared__ int   sSrc[CAPE];
    __shared__ float sRed[256];

    const int rowB = b * NN;                 // base row for this batch
    sXr[t]  = xr[(size_t)(rowB + n) * HC + t];
    sWe[t]  = We[t];
    sAtt[t] = att[t];
    const int o0 = offs[n];
    int ntot = offs[n + 1] - o0;
    if (ntot > CAPE) ntot = CAPE;
    __syncthreads();

    // ---- phase 1: per-edge logits (one wave per edge, round-robin) ----
    const int wv = t >> 6, ln = t & 63;
    const float4 xrv = reinterpret_cast<const float4*>(sXr)[ln];
    const float4 wev = reinterpret_cast<const float4*>(sWe)[ln];
    const float4 atv = reinterpret_cast<const float4*>(sAtt)[ln];

    for (int i = wv; i < ntot; i += 4) {
        const int   src = csrc[o0 + i];
        const float a   = cattr[o0 + i];
        const float4 xlv = *reinterpret_cast<const float4*>(
            xl + ((size_t)(rowB + src) * HC) + ln * 4);
        float v0 = xlv.x + xrv.x + a * wev.x; v0 = v0 > 0.f ? v0 : SLOPEK * v0;
        float v1 = xlv.y + xrv.y + a * wev.y; v1 = v1 > 0.f ? v1 : SLOPEK * v1;
        float v2 = xlv.z + xrv.z + a * wev.z; v2 = v2 > 0.f ? v2 : SLOPEK * v2;
        float v3 = xlv.w + xrv.w + a * wev.w; v3 = v3 > 0.f ? v3 : SLOPEK * v3;
        float p = v0 * atv.x + v1 * atv.y + v2 * atv.z + v3 * atv.w;
        // reduce within each 32-lane half (= one head each)
        for (int m = 16; m >= 1; m >>= 1) p += __shfl_xor(p, m);
        if (ln == 0)  { sAlpha[0][i] = p; sSrc[i] = src; }
        if (ln == 32) { sAlpha[1][i] = p; }
    }
    __syncthreads();

    // ---- phase 2: segment softmax (both heads in parallel) ----
    const int h = t >> 7, lt = t & 127;
    float mx = -1e30f;
    for (int i = lt; i < ntot; i += 128) mx = fmaxf(mx, sAlpha[h][i]);
    sRed[t] = mx; __syncthreads();
    for (int off = 64; off >= 1; off >>= 1) {
        if (lt < off) sRed[t] = fmaxf(sRed[t], sRed[t + off]);
        __syncthreads();
    }
    const float m = sRed[h << 7];
    __syncthreads();

    float sm = 0.f;
    for (int i = lt; i < ntot; i += 128) {
        float e = __expf(sAlpha[h][i] - m);
        sAlpha[h][i] = e;
        sm += e;
    }
    sRed[t] = sm; __syncthreads();
    for (int off = 64; off >= 1; off >>= 1) {
        if (lt < off) sRed[t] += sRed[t + off];
        __syncthreads();
    }
    const float inv = 1.0f / sRed[h << 7];

    // ---- phase 3: weighted aggregation; thread t owns output elem t ----
    float acc = 0.f;
    const float* xlb = xl + (size_t)rowB * HC;
    for (int i = 0; i < ntot; ++i) {
        const float a  = sAlpha[h][i];
        const int  src = sSrc[i];
        acc += a * xlb[(size_t)src * HC + t];
    }
    outp[(size_t)(rowB + n) * HC + t] = acc * inv + bias[t];
}

// -------------------------- launcher --------------------------
extern "C" void kernel_launch(void* const* d_in, const int* in_sizes, int n_in,
                              void* d_out, int out_size, void* d_ws, size_t ws_size,
                              hipStream_t stream)
{
    (void)in_sizes; (void)n_in; (void)out_size; (void)ws_size;
    const float* x    = (const float*)d_in[0];
    const int*   ei   = (const int*)d_in[1];
    const float* ea   = (const float*)d_in[2];
    const float* Wl   = (const float*)d_in[3];
    const float* bl   = (const float*)d_in[4];
    const float* Wr   = (const float*)d_in[5];
    const float* br   = (const float*)d_in[6];
    const float* We   = (const float*)d_in[7];
    const float* att  = (const float*)d_in[8];
    const float* bias = (const float*)d_in[9];
    float* outp = (float*)d_out;

    const size_t R = (size_t)BQ * NN;     // 40000 rows
    float* xl    = (float*)d_ws;
    float* xr    = xl + R * HC;
    int*   deg   = (int*)(xr + R * HC);
    int*   cnt   = deg + NN;
    float* asum  = (float*)(cnt + NN);
    float* lattr = asum + NN;
    int*   offs  = (int*)(lattr + NN);     // NN+1 entries
    int*   csrc  = offs + (NN + 2);
    float* cattr = (float*)(csrc + (EE + NN));

    // zero deg, cnt, asum (contiguous 3*NN words) — every call (graph-safe)
    hipMemsetAsync(deg, 0, sizeof(int) * NN * 3, stream);

    k_lin<<<dim3((BQ * NN) / 16, 2), 256, 0, stream>>>(x, Wl, bl, Wr, br, xl, xr);
    k_count<<<(EE + 255) / 256, 256, 0, stream>>>(ei, ea, deg, asum);
    k_scan<<<1, 1024, 0, stream>>>(deg, asum, lattr, offs);
    k_scatter<<<(EE + NN + 255) / 256, 256, 0, stream>>>(ei, ea, lattr, offs, cnt, csrc, cattr);
    k_gat<<<dim3(NN, BQ), 256, 0, stream>>>(xl, xr, offs, csrc, cattr, We, att, bias, outp);
}